// Round 6
// baseline (339.446 us; speedup 1.0000x reference)
//
#include <hip/hip_runtime.h>
#include <math.h>

#define PI_F 3.14159265358979323846f

constexpr int NM = 544;   // 32 kx-rows * 17 ky-cols of retained modes

// ---- workspace byte offsets (all 16B-aligned) ----
constexpr size_t OFF_F1T = 0;        // 17*128 cplx (col-DFT twiddle F1T[r][x], /16384 folded) 17408 B
constexpr size_t OFF_F2  = 17408;    // 128*40 floats (row-DFT twiddle F2[y][k], 20 slots/row) 20480 B
constexpr size_t OFF_G   = 37888;    // 32*128 float2 (inverse x-twiddle G[r][x])              32768 B
constexpr size_t OFF_CT  = 70656;    // 17*128 float2 (C2R cos/sin, weight folded)            17408 B
constexpr size_t OFF_XF  = 88064;    // 1024*544 float2                                       4456448 B
constexpr size_t OFF_YS  = 4544512;  // 1024*544 float2 (reduced, [ky*32+r] order)            4456448 B
constexpr size_t OFF_YP  = 9000960;  // 4*1024*544 float2 partials; reused as Z (1024*17*128)

// ---------------- K0: twiddle tables ----------------
__global__ __launch_bounds__(256) void k_tab(float* __restrict__ F1T, float* __restrict__ F2,
                                             float2* __restrict__ G, float2* __restrict__ CT) {
  const int t0 = blockIdx.x * 256 + threadIdx.x;
  const int N = gridDim.x * 256;
  const float inv = 1.0f / 16384.0f;
  for (int i = t0; i < 17 * 128; i += N) {
    int r = i >> 7, x = i & 127;
    float s, c; sincosf(-2.f * PI_F * (float)((x * r) & 127) / 128.f, &s, &c);
    F1T[2 * i] = c * inv; F1T[2 * i + 1] = s * inv;
  }
  for (int i = t0; i < 128 * 20; i += N) {
    int y = i / 20, k = i - 20 * y;
    if (k >= 17) { F2[y * 40 + 2 * k] = 0.f; F2[y * 40 + 2 * k + 1] = 0.f; }
    else {
      float s, c; sincosf(-2.f * PI_F * (float)((y * k) & 127) / 128.f, &s, &c);
      F2[y * 40 + 2 * k] = c; F2[y * 40 + 2 * k + 1] = s;
    }
  }
  for (int i = t0; i < 32 * 128; i += N) {
    int r = i >> 7, x = i & 127;
    int f = (r < 17) ? r : r + 96;
    float s, c; sincosf(2.f * PI_F * (float)((f * x) & 127) / 128.f, &s, &c);
    G[i] = make_float2(c, s);
  }
  for (int i = t0; i < 17 * 128; i += N) {
    int k = i >> 7;
    float w = k ? 2.f : 1.f;
    float s, c; sincosf(2.f * PI_F * (float)((k * (i & 127)) & 127) / 128.f, &s, &c);
    CT[i] = make_float2(w * c, w * s);
  }
}

// ---------------- K1: fused forward truncated DFT ----------------
// grid 1024 = slice (b,t), block 256 = 4 waves.
// Wave w owns r-range {4w..4w+3} (+r=16 for w0) in phase 1 and the same ky-range in phase 2.
// Phase-1 twiddles: wave-uniform global s_loads. Phase-2 twiddles: contiguous LDS b128.
__global__ __launch_bounds__(256) void k_fwd(const float* __restrict__ X,
                                             const float* __restrict__ F1T,
                                             const float* __restrict__ F2G,
                                             float2* __restrict__ Xf) {
  __shared__ float tmpL[128 * 38];   // col-DFT result, row y: 19 cplx slots (r 0..16 used)
  __shared__ float f2s[128 * 40];    // F2 copy
  const int tid = threadIdx.x;
  const int bt = blockIdx.x;

  {  // stage F2 -> LDS (coalesced float4)
    const float4* src = (const float4*)F2G;
    float4* dst = (float4*)f2s;
    for (int i = tid; i < 1280; i += 256) dst[i] = src[i];
  }

  const int wid = __builtin_amdgcn_readfirstlane(tid >> 6);
  const int lane = tid & 63;
  const bool w0 = (wid == 0);
  const int r0 = wid * 4;

  // ---- Phase 1: tmp[y][r] = sum_x X[x][y] * F1T[r][x] ----
  for (int yh = 0; yh < 2; ++yh) {
    const int y = yh * 64 + lane;
    float2 acc[5];
#pragma unroll
    for (int i = 0; i < 5; ++i) acc[i] = make_float2(0.f, 0.f);
    const float* xp = X + (size_t)bt * 16384 + y;
    for (int xc = 0; xc < 32; ++xc) {
      const float* xq = xp + xc * 512;
      float v0 = xq[0], v1 = xq[128], v2 = xq[256], v3 = xq[384];
#pragma unroll
      for (int i = 0; i < 4; ++i) {
        const float* t = F1T + ((r0 + i) << 8) + (xc << 3);   // uniform -> s_load
        acc[i].x = fmaf(v0, t[0], acc[i].x); acc[i].y = fmaf(v0, t[1], acc[i].y);
        acc[i].x = fmaf(v1, t[2], acc[i].x); acc[i].y = fmaf(v1, t[3], acc[i].y);
        acc[i].x = fmaf(v2, t[4], acc[i].x); acc[i].y = fmaf(v2, t[5], acc[i].y);
        acc[i].x = fmaf(v3, t[6], acc[i].x); acc[i].y = fmaf(v3, t[7], acc[i].y);
      }
      if (w0) {
        const float* t = F1T + (16 << 8) + (xc << 3);
        acc[4].x = fmaf(v0, t[0], acc[4].x); acc[4].y = fmaf(v0, t[1], acc[4].y);
        acc[4].x = fmaf(v1, t[2], acc[4].x); acc[4].y = fmaf(v1, t[3], acc[4].y);
        acc[4].x = fmaf(v2, t[4], acc[4].x); acc[4].y = fmaf(v2, t[5], acc[4].y);
        acc[4].x = fmaf(v3, t[6], acc[4].x); acc[4].y = fmaf(v3, t[7], acc[4].y);
      }
    }
#pragma unroll
    for (int i = 0; i < 4; ++i) {
      tmpL[y * 38 + 2 * (r0 + i)]     = acc[i].x;
      tmpL[y * 38 + 2 * (r0 + i) + 1] = acc[i].y;
    }
    if (w0) { tmpL[y * 38 + 32] = acc[4].x; tmpL[y * 38 + 33] = acc[4].y; }
  }
  __syncthreads();

  // ---- Phase 2: Xf[r][ky] = sum_y tmp[y][f(r)] * e^{-2pi i ky y/128} ----
  const int r = lane & 31;
  const int yh = lane >> 5;
  const int r2 = (r < 17) ? r : 32 - r;
  const float sgn = (r < 17) ? 1.f : -1.f;
  const int ky0 = wid * 4;
  float2 a2[5];
#pragma unroll
  for (int i = 0; i < 5; ++i) a2[i] = make_float2(0.f, 0.f);
  const float* f2p = f2s + yh * 40 + 2 * ky0;   // 16B-aligned
  const float* tp  = tmpL + yh * 38 + 2 * r2;
  for (int yl = 0; yl < 64; ++yl) {
    float2 tv = *(const float2*)tp;
    float tx = tv.x, ts = tv.y * sgn;
    float4 c01 = *(const float4*)(f2p);
    float4 c23 = *(const float4*)(f2p + 4);
    a2[0].x = fmaf(tx, c01.x, fmaf(-ts, c01.y, a2[0].x));
    a2[0].y = fmaf(tx, c01.y, fmaf( ts, c01.x, a2[0].y));
    a2[1].x = fmaf(tx, c01.z, fmaf(-ts, c01.w, a2[1].x));
    a2[1].y = fmaf(tx, c01.w, fmaf( ts, c01.z, a2[1].y));
    a2[2].x = fmaf(tx, c23.x, fmaf(-ts, c23.y, a2[2].x));
    a2[2].y = fmaf(tx, c23.y, fmaf( ts, c23.x, a2[2].y));
    a2[3].x = fmaf(tx, c23.z, fmaf(-ts, c23.w, a2[3].x));
    a2[3].y = fmaf(tx, c23.w, fmaf( ts, c23.z, a2[3].y));
    if (w0) {
      float2 c4 = *(const float2*)(f2p + 32);   // ky = 16
      a2[4].x = fmaf(tx, c4.x, fmaf(-ts, c4.y, a2[4].x));
      a2[4].y = fmaf(tx, c4.y, fmaf( ts, c4.x, a2[4].y));
    }
    f2p += 80; tp += 76;
  }
#pragma unroll
  for (int i = 0; i < 5; ++i) {
    a2[i].x += __shfl_xor(a2[i].x, 32);
    a2[i].y += __shfl_xor(a2[i].y, 32);
  }
  if (lane < 32) {
    float2* xo = Xf + (size_t)bt * NM + r * 17 + ky0;
#pragma unroll
    for (int i = 0; i < 4; ++i) xo[i] = a2[i];
    if (w0) xo[16] = a2[4];     // ky0==0 here, so r*17+16
  }
}

// ---------------- K2: skew-Hermitian channel mix (LDS-DMA pipelined) ----------------
// R6: async global->LDS staging via __builtin_amdgcn_global_load_lds (no register
// result -> compiler CANNOT sink or spill it; R0/R2/R4/R5 proved every register-
// prefetch variant collapses to load-use serial, 2.4us/iter). Double-buffered LDS,
// counted per-wave vmcnt, RAW s_barrier (no __syncthreads: it would drain vmcnt(0)).
// Block = (bhalf, t-chunk 32, c-pair): grid 512, 576 thr, LDS 2x34816B -> 2 blk/CU
// (one computes while the other barriers). Per-CU in-flight ~70 KB >> 15 KB needed
// for full HBM BW. All DMA chunks full-wave: ragged 544/1088-float rows are covered
// by an overlapping tail load that rewrites identical bytes (no masked lanes).
// XCD swizzle: each XCD owns one (bhalf,q) x 64 c-pairs -> Xf slice + tc rows L2-hot.

__device__ __forceinline__ void ldsdma16(const float* g, float* l) {
  __builtin_amdgcn_global_load_lds(
      (const __attribute__((address_space(1))) void*)g,
      (__attribute__((address_space(3))) void*)l, 16, 0, 0);
}
__device__ __forceinline__ void ldsdma4(const float* g, float* l) {
  __builtin_amdgcn_global_load_lds(
      (const __attribute__((address_space(1))) void*)g,
      (__attribute__((address_space(3))) void*)l, 4, 0, 0);
}

// 544-float row: 2 full 1024B dma16 + 256B dma4 tail over floats [480,544)
// (floats [480,512) written twice with identical data -- benign).
__device__ __forceinline__ void stage544(const float* src, float* dst, int lane) {
  ldsdma16(src + 4 * lane,        dst);
  ldsdma16(src + 256 + 4 * lane,  dst + 256);
  ldsdma4 (src + 480 + lane,      dst + 480);
}
// 1088-float row: 4 full dma16 + exact 256B dma4 tail [1024,1088).
__device__ __forceinline__ void stage1088(const float* src, float* dst, int lane) {
#pragma unroll
  for (int k = 0; k < 4; ++k) ldsdma16(src + 256 * k + 4 * lane, dst + 256 * k);
  ldsdma4(src + 1024 + lane, dst + 1024);
}

// LDS layout (floats): [0,544) Wre c0 | [544,1088) Wre c1 | [1088,1632) Wim c0 |
// [1632,2176) Wim c1 | [2176,3264) tcRe (c0 then c1) | [3264,4352) tcIm |
// [4352,8704) Xf rows b0..b0+3. Total 8704 floats = 34816 B per buffer.
__device__ __forceinline__ void stage_mix(int wid, int lane, float* buf,
                                          const float* Wre, const float* Wim,
                                          const float* Xff, int c0, int b0, int ta) {
  switch (wid) {
    case 0:
      stage544(Wre + (size_t)(c0 * 128 + ta) * NM,       buf,        lane);
      stage544(Wre + (size_t)((c0 + 1) * 128 + ta) * NM, buf + 544,  lane);
      break;
    case 1:
      stage544(Wim + (size_t)(c0 * 128 + ta) * NM,       buf + 1088, lane);
      stage544(Wim + (size_t)((c0 + 1) * 128 + ta) * NM, buf + 1632, lane);
      break;
    case 2:
      stage1088(Wre + ((size_t)ta * 128 + c0) * NM,      buf + 2176, lane);
      break;
    case 3:
      stage1088(Wim + ((size_t)ta * 128 + c0) * NM,      buf + 3264, lane);
      break;
    case 4:
      stage1088(Xff + (size_t)((b0 + 0) * 128 + ta) * NM * 2, buf + 4352 + 0 * 1088, lane);
      break;
    case 5:
      stage1088(Xff + (size_t)((b0 + 1) * 128 + ta) * NM * 2, buf + 4352 + 1 * 1088, lane);
      break;
    case 6:
      stage1088(Xff + (size_t)((b0 + 2) * 128 + ta) * NM * 2, buf + 4352 + 2 * 1088, lane);
      break;
    case 7:
      stage1088(Xff + (size_t)((b0 + 3) * 128 + ta) * NM * 2, buf + 4352 + 3 * 1088, lane);
      break;
    default: break;   // wave 8 stages nothing (K=0)
  }
}

#define WAITV(N) asm volatile("s_waitcnt vmcnt(" #N ")" ::: "memory")

__global__ __launch_bounds__(576, 2) void k_mix(const float* __restrict__ Wre,
                                                const float* __restrict__ Wim,
                                                const float2* __restrict__ Xf,
                                                float2* __restrict__ Yp) {
  __shared__ float lds[2][8704];
  const int tid = threadIdx.x;
  const int lane = tid & 63;
  const int wid = __builtin_amdgcn_readfirstlane(tid >> 6);
  const int m = tid;
  const int bid = blockIdx.x;
  const int wg = ((bid & 7) << 6) | (bid >> 3);   // bijective, 512 = 8*64
  const int bh = wg >> 8;           // b-half
  const int q  = (wg >> 6) & 3;     // t-chunk
  const int c0 = (wg & 63) << 1;    // even c-pair base
  const int b0 = bh * 4;
  const int t0 = q * 32;
  const float* Xff = (const float*)Xf;

  float2 acc0[4], acc1[4];
#pragma unroll
  for (int b = 0; b < 4; ++b) {
    acc0[b] = make_float2(0.f, 0.f);
    acc1[b] = make_float2(0.f, 0.f);
  }

  // prologue: two tiles in flight
  stage_mix(wid, lane, lds[0], Wre, Wim, Xff, c0, b0, t0 + 0);
  stage_mix(wid, lane, lds[1], Wre, Wim, Xff, c0, b0, t0 + 1);

  for (int tt = 0; tt < 32; ++tt) {
    // wait for THIS buffer's DMA (per-wave counted: keep next tile's in flight)
    if (tt < 31) {
      if (wid < 2)      WAITV(6);
      else if (wid < 8) WAITV(5);
      else              WAITV(0);
    } else {
      WAITV(0);
    }
    __builtin_amdgcn_sched_barrier(0);
    __builtin_amdgcn_s_barrier();        // now ALL waves' DMA for buf[cur] landed
    __builtin_amdgcn_sched_barrier(0);

    const float* B = &lds[tt & 1][0];
    if (m < NM) {
      float ar0 = B[m],        ar1 = B[544 + m];
      float ai0 = B[1088 + m], ai1 = B[1632 + m];
      float br0 = B[2176 + m], br1 = B[2176 + 544 + m];
      float bi0 = B[3264 + m], bi1 = B[3264 + 544 + m];
      float wr0 = ar0 - br0, wi0 = ai0 + bi0;
      float wr1 = ar1 - br1, wi1 = ai1 + bi1;
#pragma unroll
      for (int b = 0; b < 4; ++b) {
        float2 xv = *(const float2*)(B + 4352 + b * 1088 + 2 * m);
        acc0[b].x = fmaf(wr0, xv.x, fmaf(-wi0, xv.y, acc0[b].x));
        acc0[b].y = fmaf(wr0, xv.y, fmaf( wi0, xv.x, acc0[b].y));
        acc1[b].x = fmaf(wr1, xv.x, fmaf(-wi1, xv.y, acc1[b].x));
        acc1[b].y = fmaf(wr1, xv.y, fmaf( wi1, xv.x, acc1[b].y));
      }
    }
    __builtin_amdgcn_sched_barrier(0);
    __builtin_amdgcn_s_barrier();        // all waves done READING buf[cur]
    __builtin_amdgcn_sched_barrier(0);

    if (tt + 2 < 32)
      stage_mix(wid, lane, lds[tt & 1], Wre, Wim, Xff, c0, b0, t0 + tt + 2);
  }

  if (m < NM) {
    float2* yb = Yp + (size_t)q * 1024 * NM + m;
#pragma unroll
    for (int b = 0; b < 4; ++b) {
      yb[(size_t)((b0 + b) * 128 + c0)     * NM] = acc0[b];
      yb[(size_t)((b0 + b) * 128 + c0 + 1) * NM] = acc1[b];
    }
  }
}

// ---------------- K3: reduce 4 partials + permute m -> [ky*32+r] ----------------
__global__ __launch_bounds__(256) void k_red(const float2* __restrict__ Yp,
                                             float2* __restrict__ Ys) {
  int i = blockIdx.x * 256 + threadIdx.x;     // i < 1024*544
  if (i >= 1024 * NM) return;
  int bc = i / NM, m = i - bc * NM;
  int r = m / 17, ky = m - r * 17;
  float2 s = make_float2(0.f, 0.f);
#pragma unroll
  for (int ch = 0; ch < 4; ++ch) {
    float2 v = Yp[(size_t)ch * 1024 * NM + i];
    s.x += v.x; s.y += v.y;
  }
  Ys[(size_t)bc * NM + ky * 32 + r] = s;
}

// ---------------- K4: inverse row DFT ----------------
// grid 1024 = slice (b,c), block 256 = (x': 64 lanes, xh: 2, ky-parity p: 2)
__global__ __launch_bounds__(256) void k_invB(const float* __restrict__ Ys,
                                              const float2* __restrict__ G,
                                              float2* __restrict__ Z) {
  const int tid = threadIdx.x;
  const int lane = tid & 63;
  const int xh = __builtin_amdgcn_readfirstlane((tid >> 6) & 1);
  const int p  = __builtin_amdgcn_readfirstlane(tid >> 7);
  const int x = xh * 64 + lane;
  const int bc = blockIdx.x;
  float2 g[32];
#pragma unroll
  for (int r = 0; r < 32; ++r) g[r] = G[r * 128 + x];
  const float* yb = Ys + (size_t)bc * (NM * 2);
  float2* zb = Z + (size_t)bc * (17 * 128) + x;
#pragma unroll
  for (int i = 0; i < 8; ++i) {
    const int ky = 2 * i + p;
    const float* yk = yb + ky * 64;     // uniform -> s_load
    float zr = 0.f, zi = 0.f;
#pragma unroll
    for (int r = 0; r < 32; ++r) {
      float ar = yk[2 * r], ai = yk[2 * r + 1];
      zr = fmaf(ar, g[r].x, fmaf(-ai, g[r].y, zr));
      zi = fmaf(ar, g[r].y, fmaf(ai, g[r].x, zi));
    }
    zb[ky * 128] = make_float2(zr, zi);
  }
  if (p == 0) {
    const float* yk = yb + 16 * 64;
    float zr = 0.f, zi = 0.f;
#pragma unroll
    for (int r = 0; r < 32; ++r) {
      float ar = yk[2 * r], ai = yk[2 * r + 1];
      zr = fmaf(ar, g[r].x, fmaf(-ai, g[r].y, zr));
      zi = fmaf(ar, g[r].y, fmaf(ai, g[r].x, zi));
    }
    zb[16 * 128] = make_float2(zr, zi);
  }
}

// ---------------- K5: C2R reconstruction (scalar Z, per-lane cos/sin) ----------------
// grid 1024 = (b,c), block 256: lanes = yy, waves split x halves
__global__ __launch_bounds__(256) void k_invC(const float* __restrict__ Z,
                                              const float2* __restrict__ CT,
                                              float* __restrict__ out) {
  const int tid = threadIdx.x;
  const int yy = tid & 127;
  const int xh = __builtin_amdgcn_readfirstlane(tid >> 7);
  const int bc = blockIdx.x;
  float2 ct[17];
#pragma unroll
  for (int k = 0; k < 17; ++k) ct[k] = CT[k * 128 + yy];
  const float* zb = Z + (size_t)bc * (17 * 128 * 2);
  float* op = out + (size_t)bc * 16384;
#pragma unroll 2
  for (int xi = 0; xi < 64; ++xi) {
    int x = xh * 64 + xi;
    const float* zp = zb + 2 * x;        // uniform -> s_load per ky
    float s = 0.f;
#pragma unroll
    for (int k = 0; k < 17; ++k) {
      float zr = zp[k * 256], zi = zp[k * 256 + 1];
      s = fmaf(zr, ct[k].x, fmaf(-zi, ct[k].y, s));
    }
    op[x * 128 + yy] = s;                // coalesced 64 MB store
  }
}

extern "C" void kernel_launch(void* const* d_in, const int* in_sizes, int n_in,
                              void* d_out, int out_size, void* d_ws, size_t ws_size,
                              hipStream_t stream) {
  const float* X   = (const float*)d_in[0];
  const float* Wre = (const float*)d_in[1];
  const float* Wim = (const float*)d_in[2];
  float* out = (float*)d_out;

  char* ws = (char*)d_ws;
  float*  F1T = (float*)(ws + OFF_F1T);
  float*  F2  = (float*)(ws + OFF_F2);
  float2* G   = (float2*)(ws + OFF_G);
  float2* CT  = (float2*)(ws + OFF_CT);
  float2* Xf  = (float2*)(ws + OFF_XF);
  float2* Ys  = (float2*)(ws + OFF_YS);
  float2* Yp  = (float2*)(ws + OFF_YP);
  float2* Z   = Yp;                       // Yp dead after k_red; reuse as Z

  k_tab <<<32, 256, 0, stream>>>(F1T, F2, G, CT);
  k_fwd <<<1024, 256, 0, stream>>>(X, F1T, F2, Xf);
  k_mix <<<512, 576, 0, stream>>>(Wre, Wim, Xf, Yp);
  k_red <<<2176, 256, 0, stream>>>(Yp, Ys);
  k_invB<<<1024, 256, 0, stream>>>((const float*)Ys, G, Z);
  k_invC<<<1024, 256, 0, stream>>>((const float*)Z, CT, out);
}

// Round 7
// 339.197 us; speedup vs baseline: 1.0007x; 1.0007x over previous
//
#include <hip/hip_runtime.h>
#include <math.h>

#define PI_F 3.14159265358979323846f

constexpr int NM = 544;   // 32 kx-rows * 17 ky-cols of retained modes

// ---- workspace byte offsets (all 16B-aligned) ----
constexpr size_t OFF_F1T = 0;        // 17*128 cplx (col-DFT twiddle F1T[r][x], /16384 folded) 17408 B
constexpr size_t OFF_F2  = 17408;    // 128*40 floats (row-DFT twiddle F2[y][k], 20 slots/row) 20480 B
constexpr size_t OFF_G   = 37888;    // 32*128 float2 (inverse x-twiddle G[r][x])              32768 B
constexpr size_t OFF_CT  = 70656;    // 17*128 float2 (C2R cos/sin, weight folded)            17408 B
constexpr size_t OFF_XF  = 88064;    // 1024*544 float2                                       4456448 B
constexpr size_t OFF_YS  = 4544512;  // 1024*544 float2 (reduced, [ky*32+r] order)            4456448 B
constexpr size_t OFF_YP  = 9000960;  // 4*1024*544 float2 partials; reused as Z (1024*17*128)

// ---------------- K0: twiddle tables ----------------
__global__ __launch_bounds__(256) void k_tab(float* __restrict__ F1T, float* __restrict__ F2,
                                             float2* __restrict__ G, float2* __restrict__ CT) {
  const int t0 = blockIdx.x * 256 + threadIdx.x;
  const int N = gridDim.x * 256;
  const float inv = 1.0f / 16384.0f;
  for (int i = t0; i < 17 * 128; i += N) {
    int r = i >> 7, x = i & 127;
    float s, c; sincosf(-2.f * PI_F * (float)((x * r) & 127) / 128.f, &s, &c);
    F1T[2 * i] = c * inv; F1T[2 * i + 1] = s * inv;
  }
  for (int i = t0; i < 128 * 20; i += N) {
    int y = i / 20, k = i - 20 * y;
    if (k >= 17) { F2[y * 40 + 2 * k] = 0.f; F2[y * 40 + 2 * k + 1] = 0.f; }
    else {
      float s, c; sincosf(-2.f * PI_F * (float)((y * k) & 127) / 128.f, &s, &c);
      F2[y * 40 + 2 * k] = c; F2[y * 40 + 2 * k + 1] = s;
    }
  }
  for (int i = t0; i < 32 * 128; i += N) {
    int r = i >> 7, x = i & 127;
    int f = (r < 17) ? r : r + 96;
    float s, c; sincosf(2.f * PI_F * (float)((f * x) & 127) / 128.f, &s, &c);
    G[i] = make_float2(c, s);
  }
  for (int i = t0; i < 17 * 128; i += N) {
    int k = i >> 7;
    float w = k ? 2.f : 1.f;
    float s, c; sincosf(2.f * PI_F * (float)((k * (i & 127)) & 127) / 128.f, &s, &c);
    CT[i] = make_float2(w * c, w * s);
  }
}

// ---------------- K1: fused forward truncated DFT ----------------
// grid 1024 = slice (b,t), block 256 = 4 waves.
// Wave w owns r-range {4w..4w+3} (+r=16 for w0) in phase 1 and the same ky-range in phase 2.
// Phase-1 twiddles: wave-uniform global s_loads. Phase-2 twiddles: contiguous LDS b128.
__global__ __launch_bounds__(256) void k_fwd(const float* __restrict__ X,
                                             const float* __restrict__ F1T,
                                             const float* __restrict__ F2G,
                                             float2* __restrict__ Xf) {
  __shared__ float tmpL[128 * 38];   // col-DFT result, row y: 19 cplx slots (r 0..16 used)
  __shared__ float f2s[128 * 40];    // F2 copy
  const int tid = threadIdx.x;
  const int bt = blockIdx.x;

  {  // stage F2 -> LDS (coalesced float4)
    const float4* src = (const float4*)F2G;
    float4* dst = (float4*)f2s;
    for (int i = tid; i < 1280; i += 256) dst[i] = src[i];
  }

  const int wid = __builtin_amdgcn_readfirstlane(tid >> 6);
  const int lane = tid & 63;
  const bool w0 = (wid == 0);
  const int r0 = wid * 4;

  // ---- Phase 1: tmp[y][r] = sum_x X[x][y] * F1T[r][x] ----
  for (int yh = 0; yh < 2; ++yh) {
    const int y = yh * 64 + lane;
    float2 acc[5];
#pragma unroll
    for (int i = 0; i < 5; ++i) acc[i] = make_float2(0.f, 0.f);
    const float* xp = X + (size_t)bt * 16384 + y;
    for (int xc = 0; xc < 32; ++xc) {
      const float* xq = xp + xc * 512;
      float v0 = xq[0], v1 = xq[128], v2 = xq[256], v3 = xq[384];
#pragma unroll
      for (int i = 0; i < 4; ++i) {
        const float* t = F1T + ((r0 + i) << 8) + (xc << 3);   // uniform -> s_load
        acc[i].x = fmaf(v0, t[0], acc[i].x); acc[i].y = fmaf(v0, t[1], acc[i].y);
        acc[i].x = fmaf(v1, t[2], acc[i].x); acc[i].y = fmaf(v1, t[3], acc[i].y);
        acc[i].x = fmaf(v2, t[4], acc[i].x); acc[i].y = fmaf(v2, t[5], acc[i].y);
        acc[i].x = fmaf(v3, t[6], acc[i].x); acc[i].y = fmaf(v3, t[7], acc[i].y);
      }
      if (w0) {
        const float* t = F1T + (16 << 8) + (xc << 3);
        acc[4].x = fmaf(v0, t[0], acc[4].x); acc[4].y = fmaf(v0, t[1], acc[4].y);
        acc[4].x = fmaf(v1, t[2], acc[4].x); acc[4].y = fmaf(v1, t[3], acc[4].y);
        acc[4].x = fmaf(v2, t[4], acc[4].x); acc[4].y = fmaf(v2, t[5], acc[4].y);
        acc[4].x = fmaf(v3, t[6], acc[4].x); acc[4].y = fmaf(v3, t[7], acc[4].y);
      }
    }
#pragma unroll
    for (int i = 0; i < 4; ++i) {
      tmpL[y * 38 + 2 * (r0 + i)]     = acc[i].x;
      tmpL[y * 38 + 2 * (r0 + i) + 1] = acc[i].y;
    }
    if (w0) { tmpL[y * 38 + 32] = acc[4].x; tmpL[y * 38 + 33] = acc[4].y; }
  }
  __syncthreads();

  // ---- Phase 2: Xf[r][ky] = sum_y tmp[y][f(r)] * e^{-2pi i ky y/128} ----
  const int r = lane & 31;
  const int yh = lane >> 5;
  const int r2 = (r < 17) ? r : 32 - r;
  const float sgn = (r < 17) ? 1.f : -1.f;
  const int ky0 = wid * 4;
  float2 a2[5];
#pragma unroll
  for (int i = 0; i < 5; ++i) a2[i] = make_float2(0.f, 0.f);
  const float* f2p = f2s + yh * 40 + 2 * ky0;   // 16B-aligned
  const float* tp  = tmpL + yh * 38 + 2 * r2;
  for (int yl = 0; yl < 64; ++yl) {
    float2 tv = *(const float2*)tp;
    float tx = tv.x, ts = tv.y * sgn;
    float4 c01 = *(const float4*)(f2p);
    float4 c23 = *(const float4*)(f2p + 4);
    a2[0].x = fmaf(tx, c01.x, fmaf(-ts, c01.y, a2[0].x));
    a2[0].y = fmaf(tx, c01.y, fmaf( ts, c01.x, a2[0].y));
    a2[1].x = fmaf(tx, c01.z, fmaf(-ts, c01.w, a2[1].x));
    a2[1].y = fmaf(tx, c01.w, fmaf( ts, c01.z, a2[1].y));
    a2[2].x = fmaf(tx, c23.x, fmaf(-ts, c23.y, a2[2].x));
    a2[2].y = fmaf(tx, c23.y, fmaf( ts, c23.x, a2[2].y));
    a2[3].x = fmaf(tx, c23.z, fmaf(-ts, c23.w, a2[3].x));
    a2[3].y = fmaf(tx, c23.w, fmaf( ts, c23.z, a2[3].y));
    if (w0) {
      float2 c4 = *(const float2*)(f2p + 32);   // ky = 16
      a2[4].x = fmaf(tx, c4.x, fmaf(-ts, c4.y, a2[4].x));
      a2[4].y = fmaf(tx, c4.y, fmaf( ts, c4.x, a2[4].y));
    }
    f2p += 80; tp += 76;
  }
#pragma unroll
  for (int i = 0; i < 5; ++i) {
    a2[i].x += __shfl_xor(a2[i].x, 32);
    a2[i].y += __shfl_xor(a2[i].y, 32);
  }
  if (lane < 32) {
    float2* xo = Xf + (size_t)bt * NM + r * 17 + ky0;
#pragma unroll
    for (int i = 0; i < 4; ++i) xo[i] = a2[i];
    if (w0) xo[16] = a2[4];     // ky0==0 here, so r*17+16
  }
}

// ---------------- K2: skew-Hermitian channel mix (m-quad, float4 loads) ----------------
// R7: the 6-round invariant (76-86us at 70/134/160MB FETCH) was per-wave load
// WIDTH: 4B/lane wave-loads = 4 cache lines each; at 12-18 waves/CU x ~1-2
// outstanding, in-flight lines ~= 100 << 240 needed for 6.3 TB/s -> every
// schedule variant pinned at ~2 TB/s. Fix: each thread owns 4 consecutive modes
// -> all loads are float4 (16B/lane = 16 lines per wave-load). Even fully
// serialized load-use now saturates: 18 waves x 16 lines >= 288 > 240.
// Thread map: tid<544, bq=tid/136 (batch pair {bq,bq+4}), mq=tid%136, m4=4*mq.
// Per t-iter: 8 independent float4 loads (4 weight, 4 Xf), 64 FMAs, no LDS.
// Weight rows duplicate x4 across bq groups -> L1 hits; ct-vs-tc re-read dedups
// in L3 (R2: FETCH=70MB=1x unique). Grid/Yp layout/k_red unchanged from R2.
__global__ __launch_bounds__(576, 5) void k_mix(const float* __restrict__ Wre,
                                                const float* __restrict__ Wim,
                                                const float2* __restrict__ Xf,
                                                float2* __restrict__ Yp) {
  const int tid = threadIdx.x;
  if (tid >= 544) return;
  const int bid = blockIdx.x;
  const int wg = ((bid & 7) << 6) | (bid >> 3);   // bijective, 512 = 8*64
  const int q = wg >> 7;           // t-chunk
  const int c = wg & 127;
  const int t0 = q * 32;
  const int bq = tid / 136;        // 0..3
  const int mq = tid - bq * 136;   // 0..135
  const int m4 = mq << 2;

  const float* Xff = (const float*)Xf;
  const float* wct_re = Wre + (size_t)(c * 128 + t0) * NM + m4;       // +NM per t
  const float* wct_im = Wim + (size_t)(c * 128 + t0) * NM + m4;
  const float* wtc_re = Wre + ((size_t)t0 * 128 + c) * NM + m4;       // +128*NM per t
  const float* wtc_im = Wim + ((size_t)t0 * 128 + c) * NM + m4;
  const float* x0 = Xff + ((size_t)((bq    ) * 128 + t0) * NM + m4) * 2;
  const float* x1 = Xff + ((size_t)((bq + 4) * 128 + t0) * NM + m4) * 2;

  float2 a0[4], a1[4];
#pragma unroll
  for (int j = 0; j < 4; ++j) {
    a0[j] = make_float2(0.f, 0.f);
    a1[j] = make_float2(0.f, 0.f);
  }

  for (int tt = 0; tt < 32; ++tt) {
    // 8 independent float4 loads (1KB per wave-load) -- issue as a burst
    float4 cre = *(const float4*)(wct_re + (size_t)tt * NM);
    float4 cim = *(const float4*)(wct_im + (size_t)tt * NM);
    float4 tre = *(const float4*)(wtc_re + (size_t)tt * 128 * NM);
    float4 tim = *(const float4*)(wtc_im + (size_t)tt * 128 * NM);
    float4 xa0 = *(const float4*)(x0 + (size_t)tt * NM * 2);
    float4 xb0 = *(const float4*)(x0 + (size_t)tt * NM * 2 + 4);
    float4 xa1 = *(const float4*)(x1 + (size_t)tt * NM * 2);
    float4 xb1 = *(const float4*)(x1 + (size_t)tt * NM * 2 + 4);

    float wr, wi;
    wr = cre.x - tre.x; wi = cim.x + tim.x;
    a0[0].x = fmaf(wr, xa0.x, fmaf(-wi, xa0.y, a0[0].x));
    a0[0].y = fmaf(wr, xa0.y, fmaf( wi, xa0.x, a0[0].y));
    a1[0].x = fmaf(wr, xa1.x, fmaf(-wi, xa1.y, a1[0].x));
    a1[0].y = fmaf(wr, xa1.y, fmaf( wi, xa1.x, a1[0].y));
    wr = cre.y - tre.y; wi = cim.y + tim.y;
    a0[1].x = fmaf(wr, xa0.z, fmaf(-wi, xa0.w, a0[1].x));
    a0[1].y = fmaf(wr, xa0.w, fmaf( wi, xa0.z, a0[1].y));
    a1[1].x = fmaf(wr, xa1.z, fmaf(-wi, xa1.w, a1[1].x));
    a1[1].y = fmaf(wr, xa1.w, fmaf( wi, xa1.z, a1[1].y));
    wr = cre.z - tre.z; wi = cim.z + tim.z;
    a0[2].x = fmaf(wr, xb0.x, fmaf(-wi, xb0.y, a0[2].x));
    a0[2].y = fmaf(wr, xb0.y, fmaf( wi, xb0.x, a0[2].y));
    a1[2].x = fmaf(wr, xb1.x, fmaf(-wi, xb1.y, a1[2].x));
    a1[2].y = fmaf(wr, xb1.y, fmaf( wi, xb1.x, a1[2].y));
    wr = cre.w - tre.w; wi = cim.w + tim.w;
    a0[3].x = fmaf(wr, xb0.z, fmaf(-wi, xb0.w, a0[3].x));
    a0[3].y = fmaf(wr, xb0.w, fmaf( wi, xb0.z, a0[3].y));
    a1[3].x = fmaf(wr, xb1.z, fmaf(-wi, xb1.w, a1[3].x));
    a1[3].y = fmaf(wr, xb1.w, fmaf( wi, xb1.z, a1[3].y));
  }

  float* yp0 = (float*)(Yp + (size_t)q * 1024 * NM + (size_t)(bq * 128 + c) * NM + m4);
  float* yp1 = (float*)(Yp + (size_t)q * 1024 * NM + (size_t)((bq + 4) * 128 + c) * NM + m4);
  *(float4*)(yp0)     = make_float4(a0[0].x, a0[0].y, a0[1].x, a0[1].y);
  *(float4*)(yp0 + 4) = make_float4(a0[2].x, a0[2].y, a0[3].x, a0[3].y);
  *(float4*)(yp1)     = make_float4(a1[0].x, a1[0].y, a1[1].x, a1[1].y);
  *(float4*)(yp1 + 4) = make_float4(a1[2].x, a1[2].y, a1[3].x, a1[3].y);
}

// ---------------- K3: reduce 4 partials + permute m -> [ky*32+r] ----------------
__global__ __launch_bounds__(256) void k_red(const float2* __restrict__ Yp,
                                             float2* __restrict__ Ys) {
  int i = blockIdx.x * 256 + threadIdx.x;     // i < 1024*544
  if (i >= 1024 * NM) return;
  int bc = i / NM, m = i - bc * NM;
  int r = m / 17, ky = m - r * 17;
  float2 s = make_float2(0.f, 0.f);
#pragma unroll
  for (int ch = 0; ch < 4; ++ch) {
    float2 v = Yp[(size_t)ch * 1024 * NM + i];
    s.x += v.x; s.y += v.y;
  }
  Ys[(size_t)bc * NM + ky * 32 + r] = s;
}

// ---------------- K4: inverse row DFT ----------------
// grid 1024 = slice (b,c), block 256 = (x': 64 lanes, xh: 2, ky-parity p: 2)
__global__ __launch_bounds__(256) void k_invB(const float* __restrict__ Ys,
                                              const float2* __restrict__ G,
                                              float2* __restrict__ Z) {
  const int tid = threadIdx.x;
  const int lane = tid & 63;
  const int xh = __builtin_amdgcn_readfirstlane((tid >> 6) & 1);
  const int p  = __builtin_amdgcn_readfirstlane(tid >> 7);
  const int x = xh * 64 + lane;
  const int bc = blockIdx.x;
  float2 g[32];
#pragma unroll
  for (int r = 0; r < 32; ++r) g[r] = G[r * 128 + x];
  const float* yb = Ys + (size_t)bc * (NM * 2);
  float2* zb = Z + (size_t)bc * (17 * 128) + x;
#pragma unroll
  for (int i = 0; i < 8; ++i) {
    const int ky = 2 * i + p;
    const float* yk = yb + ky * 64;     // uniform -> s_load
    float zr = 0.f, zi = 0.f;
#pragma unroll
    for (int r = 0; r < 32; ++r) {
      float ar = yk[2 * r], ai = yk[2 * r + 1];
      zr = fmaf(ar, g[r].x, fmaf(-ai, g[r].y, zr));
      zi = fmaf(ar, g[r].y, fmaf(ai, g[r].x, zi));
    }
    zb[ky * 128] = make_float2(zr, zi);
  }
  if (p == 0) {
    const float* yk = yb + 16 * 64;
    float zr = 0.f, zi = 0.f;
#pragma unroll
    for (int r = 0; r < 32; ++r) {
      float ar = yk[2 * r], ai = yk[2 * r + 1];
      zr = fmaf(ar, g[r].x, fmaf(-ai, g[r].y, zr));
      zi = fmaf(ar, g[r].y, fmaf(ai, g[r].x, zi));
    }
    zb[16 * 128] = make_float2(zr, zi);
  }
}

// ---------------- K5: C2R reconstruction (scalar Z, per-lane cos/sin) ----------------
// grid 1024 = (b,c), block 256: lanes = yy, waves split x halves
__global__ __launch_bounds__(256) void k_invC(const float* __restrict__ Z,
                                              const float2* __restrict__ CT,
                                              float* __restrict__ out) {
  const int tid = threadIdx.x;
  const int yy = tid & 127;
  const int xh = __builtin_amdgcn_readfirstlane(tid >> 7);
  const int bc = blockIdx.x;
  float2 ct[17];
#pragma unroll
  for (int k = 0; k < 17; ++k) ct[k] = CT[k * 128 + yy];
  const float* zb = Z + (size_t)bc * (17 * 128 * 2);
  float* op = out + (size_t)bc * 16384;
#pragma unroll 2
  for (int xi = 0; xi < 64; ++xi) {
    int x = xh * 64 + xi;
    const float* zp = zb + 2 * x;        // uniform -> s_load per ky
    float s = 0.f;
#pragma unroll
    for (int k = 0; k < 17; ++k) {
      float zr = zp[k * 256], zi = zp[k * 256 + 1];
      s = fmaf(zr, ct[k].x, fmaf(-zi, ct[k].y, s));
    }
    op[x * 128 + yy] = s;                // coalesced 64 MB store
  }
}

extern "C" void kernel_launch(void* const* d_in, const int* in_sizes, int n_in,
                              void* d_out, int out_size, void* d_ws, size_t ws_size,
                              hipStream_t stream) {
  const float* X   = (const float*)d_in[0];
  const float* Wre = (const float*)d_in[1];
  const float* Wim = (const float*)d_in[2];
  float* out = (float*)d_out;

  char* ws = (char*)d_ws;
  float*  F1T = (float*)(ws + OFF_F1T);
  float*  F2  = (float*)(ws + OFF_F2);
  float2* G   = (float2*)(ws + OFF_G);
  float2* CT  = (float2*)(ws + OFF_CT);
  float2* Xf  = (float2*)(ws + OFF_XF);
  float2* Ys  = (float2*)(ws + OFF_YS);
  float2* Yp  = (float2*)(ws + OFF_YP);
  float2* Z   = Yp;                       // Yp dead after k_red; reuse as Z

  k_tab <<<32, 256, 0, stream>>>(F1T, F2, G, CT);
  k_fwd <<<1024, 256, 0, stream>>>(X, F1T, F2, Xf);
  k_mix <<<512, 576, 0, stream>>>(Wre, Wim, Xf, Yp);
  k_red <<<2176, 256, 0, stream>>>(Yp, Ys);
  k_invB<<<1024, 256, 0, stream>>>((const float*)Ys, G, Z);
  k_invC<<<1024, 256, 0, stream>>>((const float*)Z, CT, out);
}